// Round 4
// baseline (453.620 us; speedup 1.0000x reference)
//
#include <hip/hip_runtime.h>

#define B_ 2
#define T_ 2048
#define NH 16
#define NKV 8
#define HD 128
#define C_ 2048
#define KVD (NKV*HD)       // 1024
#define QKVD (C_ + 2*KVD)  // 4096
#define NTOK (B_*T_)       // 4096

typedef __bf16 bf16_t;
typedef __bf16 bf16x2_t __attribute__((ext_vector_type(2)));
typedef __bf16 bf16x4_t __attribute__((ext_vector_type(4)));
typedef __bf16 bf16x8_t __attribute__((ext_vector_type(8)));
typedef float f32x4_t __attribute__((ext_vector_type(4)));
typedef float f32x16_t __attribute__((ext_vector_type(16)));
typedef int i32x4_t __attribute__((ext_vector_type(4)));

__device__ __forceinline__ f32x4_t mfma16(bf16x8_t a, bf16x8_t b, f32x4_t c) {
  return __builtin_amdgcn_mfma_f32_16x16x32_bf16(a, b, c, 0, 0, 0);
}
__device__ __forceinline__ f32x16_t mfma32(bf16x8_t a, bf16x8_t b, f32x16_t c) {
  return __builtin_amdgcn_mfma_f32_32x32x16_bf16(a, b, c, 0, 0, 0);
}
__device__ __forceinline__ f32x16_t zero16() {
  f32x16_t z;
  #pragma unroll
  for (int i = 0; i < 16; i++) z[i] = 0.f;
  return z;
}
__device__ __forceinline__ int pk2(float a, float b) {
  bf16x2_t t; t[0] = (bf16_t)a; t[1] = (bf16_t)b;
  return __builtin_bit_cast(int, t);
}

// async global->LDS, 16B per lane
#define GLDS16(gp, lp) __builtin_amdgcn_global_load_lds( \
    (const __attribute__((address_space(1))) void*)(gp), \
    (__attribute__((address_space(3))) void*)(lp), 16, 0, 0)

// ---------------- fused fp32 -> bf16 convert for x / w_attn / w_proj ----------------
__global__ __launch_bounds__(256) void cvt3_kernel(const float* __restrict__ s0, bf16_t* __restrict__ d0,
                                                   const float* __restrict__ s1, bf16_t* __restrict__ d1,
                                                   const float* __restrict__ s2, bf16_t* __restrict__ d2) {
  int bid = blockIdx.x;
  const float* s; bf16_t* d; int off;
  if (bid < 8192)       { s = s0; d = d0; off = bid; }
  else if (bid < 16384) { s = s1; d = d1; off = bid - 8192; }
  else                  { s = s2; d = d2; off = bid - 16384; }
  int i = (off * 256 + threadIdx.x) * 4;
  const float4 v = *(const float4*)(s + i);
  bf16x4_t o;
  o[0] = (bf16_t)v.x; o[1] = (bf16_t)v.y; o[2] = (bf16_t)v.z; o[3] = (bf16_t)v.w;
  *(bf16x4_t*)(d + i) = o;
}

// ---------------- bf16 NT GEMM (m97 pattern): C = A B^T; out fp32 (Cf) or bf16 (Cb) ----------------
__global__ void gemm_nt(const bf16_t* __restrict__ A, const bf16_t* __restrict__ Bm,
                        float* __restrict__ Cf, bf16_t* __restrict__ Cb, int M, int N, int K) {
  __shared__ bf16_t As[128*32];
  __shared__ bf16_t Bs[128*32];
  int tid = threadIdx.x;
  int wave = tid >> 6, lane = tid & 63;
  int quad = lane >> 4, l16 = lane & 15;
  int wm = (wave >> 1) * 64, wn = (wave & 1) * 64;
  int bm = blockIdx.y * 128, bn = blockIdx.x * 128;
  int grow = wave * 32 + (lane >> 2);
  int gcol = (lane & 3) * 8;
  const bf16_t* pa = A + (size_t)(bm + grow) * K + gcol;
  const bf16_t* pb = Bm + (size_t)(bn + grow) * K + gcol;
  bf16_t* lA0 = &As[(wave * 32) * 32];
  bf16_t* lA1 = &As[(wave * 32 + 16) * 32];
  bf16_t* lB0 = &Bs[(wave * 32) * 32];
  bf16_t* lB1 = &Bs[(wave * 32 + 16) * 32];
  f32x4_t acc[4][4];
  #pragma unroll
  for (int i = 0; i < 4; i++)
    #pragma unroll
    for (int j = 0; j < 4; j++) acc[i][j] = (f32x4_t){0.f,0.f,0.f,0.f};
  for (int k0 = 0; k0 < K; k0 += 32) {
    __syncthreads();
    GLDS16(pa + k0, lA0);
    GLDS16(pa + (size_t)16 * K + k0, lA1);
    GLDS16(pb + k0, lB0);
    GLDS16(pb + (size_t)16 * K + k0, lB1);
    __syncthreads();
    bf16x8_t af[4], bfr[4];
    #pragma unroll
    for (int i = 0; i < 4; i++) {
      af[i]  = *(const bf16x8_t*)&As[(wm + i*16 + l16)*32 + quad*8];
      bfr[i] = *(const bf16x8_t*)&Bs[(wn + i*16 + l16)*32 + quad*8];
    }
    #pragma unroll
    for (int i = 0; i < 4; i++)
      #pragma unroll
      for (int j = 0; j < 4; j++)
        acc[i][j] = mfma16(af[i], bfr[j], acc[i][j]);
  }
  // C/D layout: col = lane&15, row = quad*4 + reg
  if (Cb) {
    #pragma unroll
    for (int i = 0; i < 4; i++)
      #pragma unroll
      for (int j = 0; j < 4; j++) {
        int row0 = bm + wm + i*16 + quad*4;
        int col  = bn + wn + j*16 + l16;
        #pragma unroll
        for (int r = 0; r < 4; r++)
          Cb[(size_t)(row0 + r) * N + col] = (bf16_t)acc[i][j][r];
      }
  } else {
    #pragma unroll
    for (int i = 0; i < 4; i++)
      #pragma unroll
      for (int j = 0; j < 4; j++) {
        int row0 = bm + wm + i*16 + quad*4;
        int col  = bn + wn + j*16 + l16;
        #pragma unroll
        for (int r = 0; r < 4; r++)
          Cf[(size_t)(row0 + r) * N + col] = acc[i][j][r];
      }
  }
}

// ---------------- RoPE + RMSNorm, bf16 qkv -> q/k bf16 ----------------
__global__ __launch_bounds__(256) void rope_norm_kernel(const bf16_t* __restrict__ qkv,
    const float* __restrict__ cosb, const float* __restrict__ sinb,
    bf16_t* __restrict__ qb, bf16_t* __restrict__ kb) {
  int token = blockIdx.y;
  int slot = blockIdx.x * 4 + (threadIdx.x >> 6);
  int lane = threadIdx.x & 63;
  int b = token >> 11, s = token & 2047;
  const bf16_t* row = qkv + (size_t)token * QKVD;
  int base_in = (slot < 16) ? slot * HD : C_ + (slot - 16) * HD;
  float x1 = (float)row[base_in + lane];
  float x2 = (float)row[base_in + 64 + lane];
  float c = cosb[s*64 + lane], sn = sinb[s*64 + lane];
  float y1 = x1*c + x2*sn;
  float y2 = x2*c - x1*sn;
  float ss = y1*y1 + y2*y2;
  ss += __shfl_xor(ss, 1);  ss += __shfl_xor(ss, 2);  ss += __shfl_xor(ss, 4);
  ss += __shfl_xor(ss, 8);  ss += __shfl_xor(ss, 16); ss += __shfl_xor(ss, 32);
  float r = rsqrtf(ss * (1.0f/128.0f) + 1.1920929e-07f);
  bf16_t* dst;
  if (slot < 16) {
    r *= 0.08838834764831845f * 1.4426950408889634f;  // 1/sqrt(128) * log2(e)
    dst = qb + ((size_t)(b*NH + slot) * T_ + s) * HD;
  } else {
    dst = kb + ((size_t)(b*NKV + (slot-16)) * T_ + s) * HD;
  }
  dst[lane]      = (bf16_t)(y1 * r);
  dst[lane + 64] = (bf16_t)(y2 * r);
}

// ---------------- V: transpose bf16 qkv slice to (b, kvh, d, t) ----------------
__global__ __launch_bounds__(256) void transpose_v(const bf16_t* __restrict__ qkv,
                                                   bf16_t* __restrict__ vt) {
  __shared__ bf16_t TT[64*136];   // (tok, d) pad 128->136
  int bk = blockIdx.y;            // b*8 + kv
  int b = bk >> 3, kv = bk & 7;
  int s0 = blockIdx.x * 64;
  int tid = threadIdx.x;
  int row = tid >> 2, c0 = (tid & 3) * 32;
  const bf16_t* src = qkv + (size_t)(b*T_ + s0 + row) * QKVD + C_ + KVD + kv*HD + c0;
  #pragma unroll
  for (int s4 = 0; s4 < 4; s4++)
    *(bf16x8_t*)&TT[row*136 + c0 + s4*8] = *(const bf16x8_t*)(src + s4*8);
  __syncthreads();
  #pragma unroll
  for (int s2 = 0; s2 < 2; s2++) {
    int d = (tid >> 2) + s2*64;
    #pragma unroll
    for (int s = 0; s < 2; s++) {
      int g = (tid & 3) * 8 + s*32;
      bf16x8_t pk;
      #pragma unroll
      for (int e = 0; e < 8; e++) pk[e] = TT[(g + e)*136 + d];
      *(bf16x8_t*)(vt + ((size_t)bk * HD + d) * T_ + s0 + g) = pk;
    }
  }
}

// ---------------- flash attention: 32x32x16, double-buffered staging, shuffle-P ----------------
// S^T = K Q^T: lane owns one q-row (col=l32). Two phases (qt=j, 15-j) per block ->
// uniform 34-tile blocks, 512 blocks, 2 resident/CU. K/V double-buffered: global
// loads for tile t+1 issue before compute of tile t. P C->A transform via one
// 8-dword shfl_xor(32) half-exchange (no LDS round trip).
__global__ __launch_bounds__(256, 2) void attn_kernel(const bf16_t* __restrict__ qb,
    const bf16_t* __restrict__ kb, const bf16_t* __restrict__ vt, bf16_t* __restrict__ yb) {
  __shared__ bf16_t Ksb[2][64*136];    // (key, d) pad 128->136   2 x 17408 B
  __shared__ bf16_t Vsb[2][128*72];    // (d, key) pad 64->72     2 x 18432 B  -> 71680 B
  int L = blockIdx.x;
  int bh = L & 31;
  int j = (L >> 5) & 15;
  int b = bh >> 4, h = bh & 15, kvh = h >> 1;
  int tid = threadIdx.x, wave = tid >> 6, lane = tid & 63;
  int l32 = lane & 31, half = lane >> 5;
  const bf16_t* Qp = qb + (size_t)bh * T_ * HD;
  const bf16_t* Kp = kb + (size_t)(b*NKV + kvh) * T_ * HD;
  const bf16_t* Vt = vt + (size_t)(b*NKV + kvh) * HD * T_;

  int krow = tid >> 2, kcb = (tid & 3) * 32;   // K staging: 64 rows x 128
  int vd = tid >> 1,  vcb = (tid & 1) * 32;    // V staging: 128 rows x 64

  #pragma unroll
  for (int ph = 0; ph < 2; ph++) {
    int qt = ph ? (15 - j) : j;
    int qrow = qt*128 + wave*32 + l32;
    bf16x8_t qf[8];                    // B-frag: B[k=half*8+jj][n=l32]
    #pragma unroll
    for (int kc = 0; kc < 8; kc++)
      qf[kc] = *(const bf16x8_t*)(Qp + (size_t)qrow * HD + kc*16 + half*8);

    float mrow = -1e30f, lrow = 0.f;
    f32x16_t o[4];                     // O^T: rows = d, col = q = l32
    #pragma unroll
    for (int mb = 0; mb < 4; mb++) o[mb] = zero16();

    int nkt = 2*qt + 2;
    bf16x8_t kreg[4], vreg[4];
    // prologue: stage tile 0 into buf 0
    {
      const bf16_t* srck = Kp + (size_t)krow * HD + kcb;
      const bf16_t* srcv = Vt + (size_t)vd * T_ + vcb;
      #pragma unroll
      for (int s2 = 0; s2 < 4; s2++) { kreg[s2] = *(const bf16x8_t*)(srck + s2*8);
                                       vreg[s2] = *(const bf16x8_t*)(srcv + s2*8); }
    }
    __syncthreads();  // prior phase epilogue LDS reads complete
    #pragma unroll
    for (int s2 = 0; s2 < 4; s2++) { *(bf16x8_t*)&Ksb[0][krow*136 + kcb + s2*8] = kreg[s2];
                                     *(bf16x8_t*)&Vsb[0][vd*72   + vcb + s2*8] = vreg[s2]; }

    for (int kt = 0; kt < nkt; kt++) {
      __syncthreads();  // buf[kt&1] fully staged; prior-tile reads done
      int cur = kt & 1;
      if (kt + 1 < nkt) {    // issue next tile's global loads (latency hidden by compute)
        int k1 = (kt + 1) * 64;
        const bf16_t* srck = Kp + (size_t)(k1 + krow) * HD + kcb;
        const bf16_t* srcv = Vt + (size_t)vd * T_ + k1 + vcb;
        #pragma unroll
        for (int s2 = 0; s2 < 4; s2++) { kreg[s2] = *(const bf16x8_t*)(srck + s2*8);
                                         vreg[s2] = *(const bf16x8_t*)(srcv + s2*8); }
      }
      int k0 = kt * 64;
      // S^T = K Q^T
      f32x16_t sacc[2];
      sacc[0] = zero16(); sacc[1] = zero16();
      #pragma unroll
      for (int kc = 0; kc < 8; kc++)
        #pragma unroll
        for (int mb = 0; mb < 2; mb++) {
          bf16x8_t kf = *(const bf16x8_t*)&Ksb[cur][(mb*32 + l32)*136 + kc*16 + half*8];
          sacc[mb] = mfma32(kf, qf[kc], sacc[mb]);
        }
      // causal mask near diagonal
      if (k0 + 63 > qt*128 + wave*32) {
        #pragma unroll
        for (int mb = 0; mb < 2; mb++)
          #pragma unroll
          for (int r = 0; r < 16; r++) {
            int key = k0 + mb*32 + (r&3) + 8*(r>>2) + 4*half;
            if (key > qrow) sacc[mb][r] = -1e30f;
          }
      }
      // online softmax (lane owns one q-row; one shuffle)
      float mx = -1e30f;
      #pragma unroll
      for (int mb = 0; mb < 2; mb++)
        #pragma unroll
        for (int r = 0; r < 16; r++) mx = fmaxf(mx, sacc[mb][r]);
      mx = fmaxf(mx, __shfl_xor(mx, 32));
      float mnew = fmaxf(mrow, mx);
      float alpha = exp2f(mrow - mnew);
      mrow = mnew;
      float rs = 0.f;
      #pragma unroll
      for (int mb = 0; mb < 2; mb++)
        #pragma unroll
        for (int r = 0; r < 16; r++) {
          float p = exp2f(sacc[mb][r] - mnew);
          sacc[mb][r] = p;
          rs += p;
        }
      rs += __shfl_xor(rs, 32);
      lrow = lrow * alpha + rs;
      #pragma unroll
      for (int mb = 0; mb < 4; mb++) o[mb] = o[mb] * alpha;
      // P: C-layout -> B-operand via half-exchange.
      // L/S pairs: d=0..3 -> base idx {0,2,8,10}; L adds 4*half, S adds 4*(1-half).
      int Lpk[2][4], Rpk[2][4];
      #pragma unroll
      for (int mb = 0; mb < 2; mb++)
        #pragma unroll
        for (int d = 0; d < 4; d++) {
          int base = 2*d + ((d >= 2) ? 4 : 0);
          Lpk[mb][d] = pk2(sacc[mb][base + 4*half],     sacc[mb][base + 1 + 4*half]);
          int spk    = pk2(sacc[mb][base + 4*(1-half)], sacc[mb][base + 1 + 4*(1-half)]);
          Rpk[mb][d] = __shfl_xor(spk, 32);
        }
      // O^T += V^T P
      #pragma unroll
      for (int kc = 0; kc < 4; kc++) {
        int mb = kc >> 1, q2 = (kc & 1) * 2;
        int x0 = Lpk[mb][q2], x1 = Lpk[mb][q2+1], y0 = Rpk[mb][q2], y1 = Rpk[mb][q2+1];
        i32x4_t wv;
        wv[0] = half ? y0 : x0; wv[1] = half ? y1 : x1;
        wv[2] = half ? x0 : y0; wv[3] = half ? x1 : y1;
        bf16x8_t pf = __builtin_bit_cast(bf16x8_t, wv);
        #pragma unroll
        for (int mbd = 0; mbd < 4; mbd++) {
          bf16x8_t vf = *(const bf16x8_t*)&Vsb[cur][(mbd*32 + l32)*72 + kc*16 + half*8];
          o[mbd] = mfma32(vf, pf, o[mbd]);
        }
      }
      if (kt + 1 < nkt) {  // stage next tile (after this tile's LDS reads)
        #pragma unroll
        for (int s2 = 0; s2 < 4; s2++) { *(bf16x8_t*)&Ksb[1-cur][krow*136 + kcb + s2*8] = kreg[s2];
                                         *(bf16x8_t*)&Vsb[1-cur][vd*72   + vcb + s2*8] = vreg[s2]; }
      }
    }
    // epilogue: O^T -> LDS transpose (wave-local region) -> coalesced b128 stores
    __syncthreads();  // all waves done reading bufs
    bf16_t* OL = (wave < 2) ? &Ksb[0][wave * 4352] : &Ksb[1][(wave - 2) * 4352];  // 32 x 136
    float invl = 1.0f / lrow;
    #pragma unroll
    for (int mb = 0; mb < 4; mb++)
      #pragma unroll
      for (int rr = 0; rr < 4; rr++) {
        bf16x4_t pk;
        pk[0] = (bf16_t)(o[mb][rr*4+0] * invl); pk[1] = (bf16_t)(o[mb][rr*4+1] * invl);
        pk[2] = (bf16_t)(o[mb][rr*4+2] * invl); pk[3] = (bf16_t)(o[mb][rr*4+3] * invl);
        *(bf16x4_t*)&OL[l32*136 + mb*32 + rr*8 + half*4] = pk;
      }
    int tok = qt*128 + wave*32 + l32;
    bf16_t* dst = yb + ((size_t)(b*T_ + tok) * NH + h) * HD + half*64;
    #pragma unroll
    for (int jj = 0; jj < 8; jj++)
      *(bf16x8_t*)(dst + jj*8) = *(const bf16x8_t*)&OL[l32*136 + half*64 + jj*8];
  }
}

extern "C" void kernel_launch(void* const* d_in, const int* in_sizes, int n_in,
                              void* d_out, int out_size, void* d_ws, size_t ws_size,
                              hipStream_t stream) {
  const float* x      = (const float*)d_in[0];
  const float* w_attn = (const float*)d_in[1];
  const float* w_proj = (const float*)d_in[2];
  const float* cosb   = (const float*)d_in[3];
  const float* sinb   = (const float*)d_in[4];
  float* out = (float*)d_out;

  bf16_t* xb   = (bf16_t*)d_ws;           // 8388608
  bf16_t* wab  = xb + 8388608;            // 8388608
  bf16_t* wpb  = wab + 8388608;           // 4194304
  bf16_t* qkvb = wpb + 4194304;           // 16777216
  bf16_t* qb   = qkvb + 16777216;         // 8388608
  bf16_t* kb   = qb + 8388608;            // 4194304
  bf16_t* vt   = kb + 4194304;            // 4194304 (b, kvh, d, t)
  bf16_t* yb   = vt + 4194304;            // 8388608

  cvt3_kernel<<<20480, 256, 0, stream>>>(x, xb, w_attn, wab, w_proj, wpb);

  // qkv = x @ w_attn^T : M=4096, N=4096, K=2048 (bf16 out)
  gemm_nt<<<dim3(32, 32), 256, 0, stream>>>(xb, wab, nullptr, qkvb, NTOK, QKVD, C_);

  rope_norm_kernel<<<dim3(6, 4096), 256, 0, stream>>>(qkvb, cosb, sinb, qb, kb);
  transpose_v<<<dim3(32, 16), 256, 0, stream>>>(qkvb, vt);

  attn_kernel<<<512, 256, 0, stream>>>(qb, kb, vt, yb);

  // out = y @ w_proj^T : M=4096, N=2048, K=2048 (fp32 out)
  gemm_nt<<<dim3(16, 32), 256, 0, stream>>>(yb, wpb, out, nullptr, NTOK, C_, C_);
}

// Round 5
// 342.378 us; speedup vs baseline: 1.3249x; 1.3249x over previous
//
#include <hip/hip_runtime.h>

#define B_ 2
#define T_ 2048
#define NH 16
#define NKV 8
#define HD 128
#define C_ 2048
#define KVD (NKV*HD)       // 1024
#define QKVD (C_ + 2*KVD)  // 4096
#define NTOK (B_*T_)       // 4096

typedef __bf16 bf16_t;
typedef __bf16 bf16x2_t __attribute__((ext_vector_type(2)));
typedef __bf16 bf16x4_t __attribute__((ext_vector_type(4)));
typedef __bf16 bf16x8_t __attribute__((ext_vector_type(8)));
typedef float f32x4_t __attribute__((ext_vector_type(4)));
typedef float f32x16_t __attribute__((ext_vector_type(16)));
typedef int i32x4_t __attribute__((ext_vector_type(4)));

__device__ __forceinline__ f32x4_t mfma16(bf16x8_t a, bf16x8_t b, f32x4_t c) {
  return __builtin_amdgcn_mfma_f32_16x16x32_bf16(a, b, c, 0, 0, 0);
}
__device__ __forceinline__ f32x16_t mfma32(bf16x8_t a, bf16x8_t b, f32x16_t c) {
  return __builtin_amdgcn_mfma_f32_32x32x16_bf16(a, b, c, 0, 0, 0);
}
__device__ __forceinline__ f32x16_t zero16() {
  f32x16_t z;
  #pragma unroll
  for (int i = 0; i < 16; i++) z[i] = 0.f;
  return z;
}
__device__ __forceinline__ int pk2(float a, float b) {
  bf16x2_t t; t[0] = (bf16_t)a; t[1] = (bf16_t)b;
  return __builtin_bit_cast(int, t);
}

// async global->LDS, 16B per lane
#define GLDS16(gp, lp) __builtin_amdgcn_global_load_lds( \
    (const __attribute__((address_space(1))) void*)(gp), \
    (__attribute__((address_space(3))) void*)(lp), 16, 0, 0)

// ---------------- fused fp32 -> bf16 convert for x / w_attn / w_proj ----------------
__global__ __launch_bounds__(256) void cvt3_kernel(const float* __restrict__ s0, bf16_t* __restrict__ d0,
                                                   const float* __restrict__ s1, bf16_t* __restrict__ d1,
                                                   const float* __restrict__ s2, bf16_t* __restrict__ d2) {
  int bid = blockIdx.x;
  const float* s; bf16_t* d; int off;
  if (bid < 8192)       { s = s0; d = d0; off = bid; }
  else if (bid < 16384) { s = s1; d = d1; off = bid - 8192; }
  else                  { s = s2; d = d2; off = bid - 16384; }
  int i = (off * 256 + threadIdx.x) * 4;
  const float4 v = *(const float4*)(s + i);
  bf16x4_t o;
  o[0] = (bf16_t)v.x; o[1] = (bf16_t)v.y; o[2] = (bf16_t)v.z; o[3] = (bf16_t)v.w;
  *(bf16x4_t*)(d + i) = o;
}

// ---------------- bf16 NT GEMM (m97 pattern): C = A B^T; out fp32 (Cf) or bf16 (Cb) ----------------
__global__ void gemm_nt(const bf16_t* __restrict__ A, const bf16_t* __restrict__ Bm,
                        float* __restrict__ Cf, bf16_t* __restrict__ Cb, int M, int N, int K) {
  __shared__ bf16_t As[128*32];
  __shared__ bf16_t Bs[128*32];
  int tid = threadIdx.x;
  int wave = tid >> 6, lane = tid & 63;
  int quad = lane >> 4, l16 = lane & 15;
  int wm = (wave >> 1) * 64, wn = (wave & 1) * 64;
  int bm = blockIdx.y * 128, bn = blockIdx.x * 128;
  int grow = wave * 32 + (lane >> 2);
  int gcol = (lane & 3) * 8;
  const bf16_t* pa = A + (size_t)(bm + grow) * K + gcol;
  const bf16_t* pb = Bm + (size_t)(bn + grow) * K + gcol;
  bf16_t* lA0 = &As[(wave * 32) * 32];
  bf16_t* lA1 = &As[(wave * 32 + 16) * 32];
  bf16_t* lB0 = &Bs[(wave * 32) * 32];
  bf16_t* lB1 = &Bs[(wave * 32 + 16) * 32];
  f32x4_t acc[4][4];
  #pragma unroll
  for (int i = 0; i < 4; i++)
    #pragma unroll
    for (int j = 0; j < 4; j++) acc[i][j] = (f32x4_t){0.f,0.f,0.f,0.f};
  for (int k0 = 0; k0 < K; k0 += 32) {
    __syncthreads();
    GLDS16(pa + k0, lA0);
    GLDS16(pa + (size_t)16 * K + k0, lA1);
    GLDS16(pb + k0, lB0);
    GLDS16(pb + (size_t)16 * K + k0, lB1);
    __syncthreads();
    bf16x8_t af[4], bfr[4];
    #pragma unroll
    for (int i = 0; i < 4; i++) {
      af[i]  = *(const bf16x8_t*)&As[(wm + i*16 + l16)*32 + quad*8];
      bfr[i] = *(const bf16x8_t*)&Bs[(wn + i*16 + l16)*32 + quad*8];
    }
    #pragma unroll
    for (int i = 0; i < 4; i++)
      #pragma unroll
      for (int j = 0; j < 4; j++)
        acc[i][j] = mfma16(af[i], bfr[j], acc[i][j]);
  }
  // C/D layout: col = lane&15, row = quad*4 + reg
  if (Cb) {
    #pragma unroll
    for (int i = 0; i < 4; i++)
      #pragma unroll
      for (int j = 0; j < 4; j++) {
        int row0 = bm + wm + i*16 + quad*4;
        int col  = bn + wn + j*16 + l16;
        #pragma unroll
        for (int r = 0; r < 4; r++)
          Cb[(size_t)(row0 + r) * N + col] = (bf16_t)acc[i][j][r];
      }
  } else {
    #pragma unroll
    for (int i = 0; i < 4; i++)
      #pragma unroll
      for (int j = 0; j < 4; j++) {
        int row0 = bm + wm + i*16 + quad*4;
        int col  = bn + wn + j*16 + l16;
        #pragma unroll
        for (int r = 0; r < 4; r++)
          Cf[(size_t)(row0 + r) * N + col] = acc[i][j][r];
      }
  }
}

// ---------------- RoPE + RMSNorm, bf16 qkv -> q/k bf16 ----------------
__global__ __launch_bounds__(256) void rope_norm_kernel(const bf16_t* __restrict__ qkv,
    const float* __restrict__ cosb, const float* __restrict__ sinb,
    bf16_t* __restrict__ qb, bf16_t* __restrict__ kb) {
  int token = blockIdx.y;
  int slot = blockIdx.x * 4 + (threadIdx.x >> 6);
  int lane = threadIdx.x & 63;
  int b = token >> 11, s = token & 2047;
  const bf16_t* row = qkv + (size_t)token * QKVD;
  int base_in = (slot < 16) ? slot * HD : C_ + (slot - 16) * HD;
  float x1 = (float)row[base_in + lane];
  float x2 = (float)row[base_in + 64 + lane];
  float c = cosb[s*64 + lane], sn = sinb[s*64 + lane];
  float y1 = x1*c + x2*sn;
  float y2 = x2*c - x1*sn;
  float ss = y1*y1 + y2*y2;
  ss += __shfl_xor(ss, 1);  ss += __shfl_xor(ss, 2);  ss += __shfl_xor(ss, 4);
  ss += __shfl_xor(ss, 8);  ss += __shfl_xor(ss, 16); ss += __shfl_xor(ss, 32);
  float r = rsqrtf(ss * (1.0f/128.0f) + 1.1920929e-07f);
  bf16_t* dst;
  if (slot < 16) {
    r *= 0.08838834764831845f * 1.4426950408889634f;  // 1/sqrt(128) * log2(e)
    dst = qb + ((size_t)(b*NH + slot) * T_ + s) * HD;
  } else {
    dst = kb + ((size_t)(b*NKV + (slot-16)) * T_ + s) * HD;
  }
  dst[lane]      = (bf16_t)(y1 * r);
  dst[lane + 64] = (bf16_t)(y2 * r);
}

// ---------------- V: transpose bf16 qkv slice to (b, kvh, d, t) ----------------
__global__ __launch_bounds__(256) void transpose_v(const bf16_t* __restrict__ qkv,
                                                   bf16_t* __restrict__ vt) {
  __shared__ bf16_t TT[64*136];   // (tok, d) pad 128->136
  int bk = blockIdx.y;            // b*8 + kv
  int b = bk >> 3, kv = bk & 7;
  int s0 = blockIdx.x * 64;
  int tid = threadIdx.x;
  int row = tid >> 2, c0 = (tid & 3) * 32;
  const bf16_t* src = qkv + (size_t)(b*T_ + s0 + row) * QKVD + C_ + KVD + kv*HD + c0;
  #pragma unroll
  for (int s4 = 0; s4 < 4; s4++)
    *(bf16x8_t*)&TT[row*136 + c0 + s4*8] = *(const bf16x8_t*)(src + s4*8);
  __syncthreads();
  #pragma unroll
  for (int s2 = 0; s2 < 2; s2++) {
    int d = (tid >> 2) + s2*64;
    #pragma unroll
    for (int s = 0; s < 2; s++) {
      int g = (tid & 3) * 8 + s*32;
      bf16x8_t pk;
      #pragma unroll
      for (int e = 0; e < 8; e++) pk[e] = TT[(g + e)*136 + d];
      *(bf16x8_t*)(vt + ((size_t)bk * HD + d) * T_ + s0 + g) = pk;
    }
  }
}

// ---------------- flash attention: 32x32x16, 256 uniform blocks, dbuf staging, shuffle-P ----------------
// S^T = K Q^T: lane owns one q-row (col=l32). Phases qt = j and 15-j inside each block ->
// 256 blocks x 34 tiles, exactly 1 block/CU. K/V double-buffered (reg prefetch).
// P C->B-operand transform: compile-time-indexed packs + cndmask selects + shfl_xor(32).
__global__ __launch_bounds__(256, 1) void attn_kernel(const bf16_t* __restrict__ qb,
    const bf16_t* __restrict__ kb, const bf16_t* __restrict__ vt, bf16_t* __restrict__ yb) {
  __shared__ bf16_t Ksb[2][64*136];    // (key, d) pad 128->136   2 x 17408 B
  __shared__ bf16_t Vsb[2][128*72];    // (d, key) pad 64->72     2 x 18432 B  -> 71680 B
  int L = blockIdx.x;
  int bh = L & 31;
  int j = (L >> 5) & 7;                // 0..7; phases cover qt = j and 15-j (16 q-tiles once)
  int b = bh >> 4, h = bh & 15, kvh = h >> 1;
  int tid = threadIdx.x, wave = tid >> 6, lane = tid & 63;
  int l32 = lane & 31, half = lane >> 5;
  const bf16_t* Qp = qb + (size_t)bh * T_ * HD;
  const bf16_t* Kp = kb + (size_t)(b*NKV + kvh) * T_ * HD;
  const bf16_t* Vt = vt + (size_t)(b*NKV + kvh) * HD * T_;

  int krow = tid >> 2, kcb = (tid & 3) * 32;   // K staging: 64 rows x 128
  int vd = tid >> 1,  vcb = (tid & 1) * 32;    // V staging: 128 rows x 64

  #pragma unroll
  for (int ph = 0; ph < 2; ph++) {
    int qt = ph ? (15 - j) : j;
    int qrow = qt*128 + wave*32 + l32;
    bf16x8_t qf[8];                    // B-frag: B[k=half*8+jj][n=l32]
    #pragma unroll
    for (int kc = 0; kc < 8; kc++)
      qf[kc] = *(const bf16x8_t*)(Qp + (size_t)qrow * HD + kc*16 + half*8);

    float mrow = -1e30f, lrow = 0.f;
    f32x16_t o[4];                     // O^T: rows = d, col = q = l32
    #pragma unroll
    for (int mb = 0; mb < 4; mb++) o[mb] = zero16();

    int nkt = 2*qt + 2;
    bf16x8_t kreg[4], vreg[4];
    // prologue: stage tile 0 into buf 0
    {
      const bf16_t* srck = Kp + (size_t)krow * HD + kcb;
      const bf16_t* srcv = Vt + (size_t)vd * T_ + vcb;
      #pragma unroll
      for (int s2 = 0; s2 < 4; s2++) { kreg[s2] = *(const bf16x8_t*)(srck + s2*8);
                                       vreg[s2] = *(const bf16x8_t*)(srcv + s2*8); }
    }
    __syncthreads();  // prior phase epilogue LDS reads complete
    #pragma unroll
    for (int s2 = 0; s2 < 4; s2++) { *(bf16x8_t*)&Ksb[0][krow*136 + kcb + s2*8] = kreg[s2];
                                     *(bf16x8_t*)&Vsb[0][vd*72   + vcb + s2*8] = vreg[s2]; }

    for (int kt = 0; kt < nkt; kt++) {
      __syncthreads();  // buf[kt&1] fully staged; prior-tile reads done
      int cur = kt & 1;
      if (kt + 1 < nkt) {    // issue next tile's global loads (latency hidden by compute)
        int k1 = (kt + 1) * 64;
        const bf16_t* srck = Kp + (size_t)(k1 + krow) * HD + kcb;
        const bf16_t* srcv = Vt + (size_t)vd * T_ + k1 + vcb;
        #pragma unroll
        for (int s2 = 0; s2 < 4; s2++) { kreg[s2] = *(const bf16x8_t*)(srck + s2*8);
                                         vreg[s2] = *(const bf16x8_t*)(srcv + s2*8); }
      }
      int k0 = kt * 64;
      // S^T = K Q^T
      f32x16_t sacc[2];
      sacc[0] = zero16(); sacc[1] = zero16();
      #pragma unroll
      for (int kc = 0; kc < 8; kc++)
        #pragma unroll
        for (int mb = 0; mb < 2; mb++) {
          bf16x8_t kf = *(const bf16x8_t*)&Ksb[cur][(mb*32 + l32)*136 + kc*16 + half*8];
          sacc[mb] = mfma32(kf, qf[kc], sacc[mb]);
        }
      // causal mask near diagonal
      if (k0 + 63 > qt*128 + wave*32) {
        #pragma unroll
        for (int mb = 0; mb < 2; mb++)
          #pragma unroll
          for (int r = 0; r < 16; r++) {
            int key = k0 + mb*32 + (r&3) + 8*(r>>2) + 4*half;
            if (key > qrow) sacc[mb][r] = -1e30f;
          }
      }
      // online softmax (lane owns one q-row; one shuffle)
      float mx = -1e30f;
      #pragma unroll
      for (int mb = 0; mb < 2; mb++)
        #pragma unroll
        for (int r = 0; r < 16; r++) mx = fmaxf(mx, sacc[mb][r]);
      mx = fmaxf(mx, __shfl_xor(mx, 32));
      float mnew = fmaxf(mrow, mx);
      float alpha = exp2f(mrow - mnew);
      mrow = mnew;
      float rs = 0.f;
      #pragma unroll
      for (int mb = 0; mb < 2; mb++)
        #pragma unroll
        for (int r = 0; r < 16; r++) {
          float p = exp2f(sacc[mb][r] - mnew);
          sacc[mb][r] = p;
          rs += p;
        }
      rs += __shfl_xor(rs, 32);
      lrow = lrow * alpha + rs;
      #pragma unroll
      for (int mb = 0; mb < 4; mb++) o[mb] = o[mb] * alpha;
      // P pack: all compile-time indices. P2[mb][g] packs regs {4g..4g+3} (rows 8g+4*half_holder+0..3)
      int P2[2][4][2];
      #pragma unroll
      for (int mb = 0; mb < 2; mb++)
        #pragma unroll
        for (int g = 0; g < 4; g++) {
          P2[mb][g][0] = pk2(sacc[mb][4*g+0], sacc[mb][4*g+1]);
          P2[mb][g][1] = pk2(sacc[mb][4*g+2], sacc[mb][4*g+3]);
        }
      // O^T += V^T P ; pf[kc] = keys kc*16 + half*8 + 0..7
      #pragma unroll
      for (int kc = 0; kc < 4; kc++) {
        int mb = kc >> 1, c = kc & 1;
        // own group go = 2c+half; send group gs = 2c+1-half (what partner needs)
        int o0 = half ? P2[mb][2*c+1][0] : P2[mb][2*c][0];
        int o1 = half ? P2[mb][2*c+1][1] : P2[mb][2*c][1];
        int s0 = half ? P2[mb][2*c][0]   : P2[mb][2*c+1][0];
        int s1 = half ? P2[mb][2*c][1]   : P2[mb][2*c+1][1];
        int r0 = __shfl_xor(s0, 32);
        int r1 = __shfl_xor(s1, 32);
        i32x4_t wv;
        wv[0] = half ? r0 : o0;  // quadA (half0-held rows) first
        wv[1] = half ? r1 : o1;
        wv[2] = half ? o0 : r0;  // quadB (half1-held rows)
        wv[3] = half ? o1 : r1;
        bf16x8_t pf = __builtin_bit_cast(bf16x8_t, wv);
        #pragma unroll
        for (int mbd = 0; mbd < 4; mbd++) {
          bf16x8_t vf = *(const bf16x8_t*)&Vsb[cur][(mbd*32 + l32)*72 + kc*16 + half*8];
          o[mbd] = mfma32(vf, pf, o[mbd]);
        }
      }
      if (kt + 1 < nkt) {  // stage next tile (after this tile's LDS reads)
        #pragma unroll
        for (int s2 = 0; s2 < 4; s2++) { *(bf16x8_t*)&Ksb[1-cur][krow*136 + kcb + s2*8] = kreg[s2];
                                         *(bf16x8_t*)&Vsb[1-cur][vd*72   + vcb + s2*8] = vreg[s2]; }
      }
    }
    // epilogue: O^T -> LDS transpose (wave-local region) -> coalesced b128 stores
    __syncthreads();  // all waves done reading bufs
    bf16_t* OL = (wave < 2) ? &Ksb[0][wave * 4352] : &Ksb[1][(wave - 2) * 4352];  // 32 x 136
    float invl = 1.0f / lrow;
    #pragma unroll
    for (int mb = 0; mb < 4; mb++)
      #pragma unroll
      for (int rr = 0; rr < 4; rr++) {
        bf16x4_t pk;
        pk[0] = (bf16_t)(o[mb][rr*4+0] * invl); pk[1] = (bf16_t)(o[mb][rr*4+1] * invl);
        pk[2] = (bf16_t)(o[mb][rr*4+2] * invl); pk[3] = (bf16_t)(o[mb][rr*4+3] * invl);
        *(bf16x4_t*)&OL[l32*136 + mb*32 + rr*8 + half*4] = pk;
      }
    int tok = qt*128 + wave*32 + l32;
    bf16_t* dst = yb + ((size_t)(b*T_ + tok) * NH + h) * HD + half*64;
    #pragma unroll
    for (int jj = 0; jj < 8; jj++)
      *(bf16x8_t*)(dst + jj*8) = *(const bf16x8_t*)&OL[l32*136 + half*64 + jj*8];
  }
}

extern "C" void kernel_launch(void* const* d_in, const int* in_sizes, int n_in,
                              void* d_out, int out_size, void* d_ws, size_t ws_size,
                              hipStream_t stream) {
  const float* x      = (const float*)d_in[0];
  const float* w_attn = (const float*)d_in[1];
  const float* w_proj = (const float*)d_in[2];
  const float* cosb   = (const float*)d_in[3];
  const float* sinb   = (const float*)d_in[4];
  float* out = (float*)d_out;

  bf16_t* xb   = (bf16_t*)d_ws;           // 8388608
  bf16_t* wab  = xb + 8388608;            // 8388608
  bf16_t* wpb  = wab + 8388608;           // 4194304
  bf16_t* qkvb = wpb + 4194304;           // 16777216
  bf16_t* qb   = qkvb + 16777216;         // 8388608
  bf16_t* kb   = qb + 8388608;            // 4194304
  bf16_t* vt   = kb + 4194304;            // 4194304 (b, kvh, d, t)
  bf16_t* yb   = vt + 4194304;            // 8388608

  cvt3_kernel<<<20480, 256, 0, stream>>>(x, xb, w_attn, wab, w_proj, wpb);

  // qkv = x @ w_attn^T : M=4096, N=4096, K=2048 (bf16 out)
  gemm_nt<<<dim3(32, 32), 256, 0, stream>>>(xb, wab, nullptr, qkvb, NTOK, QKVD, C_);

  rope_norm_kernel<<<dim3(6, 4096), 256, 0, stream>>>(qkvb, cosb, sinb, qb, kb);
  transpose_v<<<dim3(32, 16), 256, 0, stream>>>(qkvb, vt);

  attn_kernel<<<256, 256, 0, stream>>>(qb, kb, vt, yb);

  // out = y @ w_proj^T : M=4096, N=2048, K=2048 (fp32 out)
  gemm_nt<<<dim3(16, 32), 256, 0, stream>>>(yb, wpb, out, nullptr, NTOK, C_, C_);
}